// Round 1
// 214.532 us; speedup vs baseline: 1.0715x; 1.0715x over previous
//
#include <hip/hip_runtime.h>
#include <hip/hip_bf16.h>
#include <hip/hip_fp8.h>

#define SEQ 4096
#define DIM 1024

using f32x4  = __attribute__((ext_vector_type(4))) float;
using bf16x8 = __attribute__((ext_vector_type(8))) short;

static __device__ __forceinline__ float bf2f(unsigned short u) {
  unsigned int x = ((unsigned int)u) << 16;
  return __builtin_bit_cast(float, x);
}
static __device__ __forceinline__ unsigned short f2bf(float f) {
  unsigned int x = __builtin_bit_cast(unsigned int, f);
  unsigned int r = (x + 0x7fff + ((x >> 16) & 1)) >> 16;  // RNE
  return (unsigned short)r;
}
static __device__ __forceinline__ unsigned char f2fp8(float f) {
  __hip_fp8_e4m3 h(f);  // OCP e4m3fn
  return h.__x;
}
static __device__ __forceinline__ float fp82f(unsigned char u) {
  __hip_fp8_e4m3 h;
  h.__x = u;
  return (float)h;
}

// ---- x -> bf16; out[:, :1024] = x (fp32); out[:, 1024:2048] = 0 ----
__global__ __launch_bounds__(256) void convert_x_kernel(
    const float* __restrict__ x, unsigned short* __restrict__ xb,
    float* __restrict__ out) {
  int idx = blockIdx.x * 256 + threadIdx.x;  // one thread per 4 floats
  int e = idx * 4;
  int i = e >> 10;
  int d = e & 1023;
  float4 v = *(const float4*)(x + (size_t)e);
  *(float4*)(out + (size_t)i * 2048 + d) = v;
  *(float4*)(out + (size_t)i * 2048 + 1024 + d) = make_float4(0.f, 0.f, 0.f, 0.f);
  ushort4 p;
  p.x = f2bf(v.x); p.y = f2bf(v.y); p.z = f2bf(v.z); p.w = f2bf(v.w);
  *(ushort4*)(xb + (size_t)e) = p;
}

// ---- prep: 3x W transpose ([in][out] f32 -> [out][in] bf16) + bias concat ----
__global__ __launch_bounds__(256) void prep_kernel(
    const float* __restrict__ Wq, const float* __restrict__ Wk,
    const float* __restrict__ Wv, const float* __restrict__ bq,
    const float* __restrict__ bk, const float* __restrict__ bv,
    unsigned short* __restrict__ Wcat, float* __restrict__ bcat) {
  int b = blockIdx.x;
  if (b < 3072) {
    int m  = b >> 10;
    int tt = b & 1023;
    const float* in = (m == 0) ? Wq : (m == 1) ? Wk : Wv;
    unsigned short* out = Wcat + (size_t)m * DIM * DIM;
    __shared__ float tile[32][33];
    int bx = (tt & 31) * 32, by = (tt >> 5) * 32;
    int tx = threadIdx.x & 31, ty = threadIdx.x >> 5;
#pragma unroll
    for (int r = 0; r < 32; r += 8)
      tile[ty + r][tx] = in[(size_t)(by + ty + r) * DIM + bx + tx];
    __syncthreads();
#pragma unroll
    for (int r = 0; r < 32; r += 8)
      out[(size_t)(bx + ty + r) * DIM + by + tx] = f2bf(tile[tx][ty + r]);
  } else {
    int i = (b - 3072) * 256 + threadIdx.x;  // 12 blocks -> 3072 elems
    float v = (i < 1024) ? bq[i] : (i < 2048 ? bk[i - 1024] : bv[i - 2048]);
    bcat[i] = v;
  }
}

// ---- transpose V (bf16 [4096][1024]) -> Vt (fp8 [1024][4096]) + zero lrow ----
__global__ __launch_bounds__(256) void transpose_v_kernel(
    const unsigned short* __restrict__ in, int ld_in,
    unsigned char* __restrict__ out, int ld_out,
    float* __restrict__ lrow) {
  if (blockIdx.y == 0 && blockIdx.x < 16)
    lrow[blockIdx.x * 256 + threadIdx.x] = 0.0f;
  __shared__ unsigned short tile[32][33];
  int bx = blockIdx.x * 32;  // c base (V col)
  int by = blockIdx.y * 32;  // r base (V row)
  int tx = threadIdx.x & 31;
  int ty = threadIdx.x >> 5;
#pragma unroll
  for (int r = 0; r < 32; r += 8)
    tile[ty + r][tx] = in[(size_t)(by + ty + r) * ld_in + bx + tx];
  __syncthreads();
#pragma unroll
  for (int r = 0; r < 32; r += 8)
    out[(size_t)(bx + ty + r) * ld_out + by + tx] = f2fp8(bf2f(tile[tx][ty + r]));
}

// ---- QKV GEMM (bf16, BK=64, 8-slot XOR swizzle) ----
// 2-phase double-buffered pipeline: counted vmcnt(8), raw barriers (no
// __syncthreads drain). C = Xb @ Wcat^T + bcat; epilogue routes
// Q cols -> fp8 (x1/32), K cols -> fp8, V cols -> bf16.
__global__ __launch_bounds__(256) void gemm_qkv(
    const unsigned short* __restrict__ A, const unsigned short* __restrict__ B,
    const float* __restrict__ bias,
    unsigned char* __restrict__ Qf8, unsigned char* __restrict__ Kf8,
    unsigned short* __restrict__ Vb) {
  const int tid  = threadIdx.x;
  const int wave = tid >> 6;
  const int lane = tid & 63;
  const int wm = wave >> 1, wn = wave & 1;

  int lin = blockIdx.x + 24 * blockIdx.y;
  int xcd = lin & 7, idx = lin >> 3;  // idx in [0,96)
  const int i0 = (xcd * 4 + idx / 24) * 128;
  const int j0 = (idx % 24) * 128;
  const int lda = DIM, ldb = DIM;

  __shared__ unsigned short lA[2][128 * 64];  // 2 x 16 KB
  __shared__ unsigned short lB[2][128 * 64];  // 2 x 16 KB

  f32x4 acc[4][4];
#pragma unroll
  for (int a = 0; a < 4; ++a)
#pragma unroll
    for (int b = 0; b < 4; ++b) acc[a][b] = (f32x4){0.f, 0.f, 0.f, 0.f};

  const int l15  = lane & 15;
  const int quad = lane >> 4;
  const int r7   = l15 & 7;
  const int cbase = wave * 256;

  // stage one 128x64 A-tile + B-tile into buffer `buf` (8 gll / thread)
  auto stage = [&](int buf, int kt) {
    const unsigned short* gA = A + (size_t)i0 * lda + kt;
    const unsigned short* gB = B + (size_t)j0 * ldb + kt;
#pragma unroll
    for (int t = 0; t < 4; ++t) {
      int c  = cbase + t * 64 + lane;
      int r  = c >> 3;
      int g  = (c & 7) ^ (r & 7);
      __builtin_amdgcn_global_load_lds(
          (const __attribute__((address_space(1))) void*)(gA + (size_t)r * lda + g * 8),
          (__attribute__((address_space(3))) void*)(&lA[buf][c * 8]), 16, 0, 0);
      __builtin_amdgcn_global_load_lds(
          (const __attribute__((address_space(1))) void*)(gB + (size_t)r * ldb + g * 8),
          (__attribute__((address_space(3))) void*)(&lB[buf][c * 8]), 16, 0, 0);
    }
  };

  stage(0, 0);
  int cur = 0;
  for (int kt = 0; kt < DIM; kt += 64) {
    if (kt + 64 < DIM) {
      stage(cur ^ 1, kt + 64);
      asm volatile("s_waitcnt vmcnt(8)" ::: "memory");  // current tile landed
    } else {
      asm volatile("s_waitcnt vmcnt(0)" ::: "memory");
    }
    __builtin_amdgcn_s_barrier();
    asm volatile("" ::: "memory");
    const unsigned short* sA = lA[cur];
    const unsigned short* sB = lB[cur];
#pragma unroll
    for (int kf = 0; kf < 2; ++kf) {
      bf16x8 af[4], bfr[4];
#pragma unroll
      for (int mt = 0; mt < 4; ++mt)
        af[mt] = *(const bf16x8*)&sA[(wm * 64 + mt * 16 + l15) * 64 + ((kf * 4 + quad) ^ r7) * 8];
#pragma unroll
      for (int nt = 0; nt < 4; ++nt)
        bfr[nt] = *(const bf16x8*)&sB[(wn * 64 + nt * 16 + l15) * 64 + ((kf * 4 + quad) ^ r7) * 8];
#pragma unroll
      for (int mt = 0; mt < 4; ++mt)
#pragma unroll
        for (int nt = 0; nt < 4; ++nt)
          acc[mt][nt] = __builtin_amdgcn_mfma_f32_16x16x32_bf16(af[mt], bfr[nt], acc[mt][nt], 0, 0, 0);
    }
    asm volatile("" ::: "memory");
    __builtin_amdgcn_s_barrier();
    asm volatile("" ::: "memory");
    cur ^= 1;
  }

  // epilogue: route to Qf8 / Kf8 / Vb (matrix select is wave-uniform per nt)
#pragma unroll
  for (int nt = 0; nt < 4; ++nt) {
    int cb  = j0 + wn * 64 + nt * 16;  // 16-col tile lies in one matrix
    int mat = cb >> 10;                // 0=Q, 1=K, 2=V
    int gc  = cb + l15;
    float bv = bias[gc];
    if (mat == 0) {
#pragma unroll
      for (int mt = 0; mt < 4; ++mt) {
        int gr0 = i0 + wm * 64 + mt * 16 + quad * 4;
#pragma unroll
        for (int r = 0; r < 4; ++r)
          Qf8[(size_t)(gr0 + r) * DIM + gc] = f2fp8((acc[mt][nt][r] + bv) * 0.03125f);
      }
    } else if (mat == 1) {
#pragma unroll
      for (int mt = 0; mt < 4; ++mt) {
        int gr0 = i0 + wm * 64 + mt * 16 + quad * 4;
#pragma unroll
        for (int r = 0; r < 4; ++r)
          Kf8[(size_t)(gr0 + r) * DIM + (gc - 1024)] = f2fp8(acc[mt][nt][r] + bv);
      }
    } else {
#pragma unroll
      for (int mt = 0; mt < 4; ++mt) {
        int gr0 = i0 + wm * 64 + mt * 16 + quad * 4;
#pragma unroll
        for (int r = 0; r < 4; ++r)
          Vb[(size_t)(gr0 + r) * DIM + (gc - 2048)] = f2bf(acc[mt][nt][r] + bv);
      }
    }
  }
}

// ---- fp8 BT GEMM, BK=128, 8-slot XOR swizzle, 2-phase dbuf pipeline ----
// MODE 1: scores (528 upper-tri tiles, 66/XCD). Epilogue: e=exp(S-4) fp8,
//         row-sums atomically into lrow.
// MODE 2: PV split-K (z=4 x 1024), identity grid (XCD-balanced).
//         Epilogue scales by 1/lrow, fp32 atomicAdd into out.
template <int MODE>
__global__ __launch_bounds__(256) void gemm_fp8(
    const unsigned char* __restrict__ A, int lda,
    const unsigned char* __restrict__ B, int ldb,
    unsigned char* __restrict__ Cb, float* __restrict__ Cf,
    float* __restrict__ lrow, int ldc, int ccol, int K) {
  const int tid  = threadIdx.x;
  const int wave = tid >> 6;
  const int lane = tid & 63;
  const int wm = wave >> 1, wn = wave & 1;

  int i0, j0, kstart, kend;
  if (MODE == 1) {
    int b = blockIdx.x;
    int t = (b & 7) * 66 + (b >> 3);
    int bi = (int)floorf((65.0f - sqrtf(4225.0f - 8.0f * (float)t)) * 0.5f);
    while (bi > 0 && (bi * (65 - bi)) / 2 > t) --bi;
    while (((bi + 1) * (64 - bi)) / 2 <= t) ++bi;
    int bj = bi + (t - (bi * (65 - bi)) / 2);
    i0 = bi * 128; j0 = bj * 128; kstart = 0; kend = K;
  } else {
    i0 = blockIdx.y * 128; j0 = blockIdx.x * 128;
    int kc0 = blockIdx.z * 1024;
    kend = kc0 + 1024;
    if (kend <= i0) return;           // chunk entirely in zero region
    kstart = (kc0 > i0) ? kc0 : i0;   // Pr cols < i0 are exactly zero
  }

  __shared__ unsigned char lA[2][128 * 128];  // 2 x 16 KB
  __shared__ unsigned char lB[2][128 * 128];  // 2 x 16 KB

  f32x4 acc[4][4];
#pragma unroll
  for (int a = 0; a < 4; ++a)
#pragma unroll
    for (int b = 0; b < 4; ++b) acc[a][b] = (f32x4){0.f, 0.f, 0.f, 0.f};

  const int l15  = lane & 15;
  const int quad = lane >> 4;
  const int r7   = l15 & 7;
  const int cbase = wave * 256;  // 1024 chunks of 16B per matrix, 4/thread

  // stage one 128x128B A-tile + B-tile into buffer `buf` (8 gll / thread)
  auto stage = [&](int buf, int kt) {
    const unsigned char* gA = A + (size_t)i0 * lda + kt;
    const unsigned char* gB = B + (size_t)j0 * ldb + kt;
#pragma unroll
    for (int t = 0; t < 4; ++t) {
      int c  = cbase + t * 64 + lane;
      int r  = c >> 3;
      int g  = (c & 7) ^ (r & 7);
      __builtin_amdgcn_global_load_lds(
          (const __attribute__((address_space(1))) void*)(gA + (size_t)r * lda + g * 16),
          (__attribute__((address_space(3))) void*)(&lA[buf][c * 16]), 16, 0, 0);
      __builtin_amdgcn_global_load_lds(
          (const __attribute__((address_space(1))) void*)(gB + (size_t)r * ldb + g * 16),
          (__attribute__((address_space(3))) void*)(&lB[buf][c * 16]), 16, 0, 0);
    }
  };

  stage(0, kstart);
  int cur = 0;
  for (int kt = kstart; kt < kend; kt += 128) {
    if (kt + 128 < kend) {
      stage(cur ^ 1, kt + 128);
      asm volatile("s_waitcnt vmcnt(8)" ::: "memory");  // current tile landed
    } else {
      asm volatile("s_waitcnt vmcnt(0)" ::: "memory");
    }
    __builtin_amdgcn_s_barrier();
    asm volatile("" ::: "memory");
    const unsigned char* sA = lA[cur];
    const unsigned char* sB = lB[cur];
#pragma unroll
    for (int kf = 0; kf < 4; ++kf) {
      long av[4], bvv[4];
#pragma unroll
      for (int mt = 0; mt < 4; ++mt) {
        int row = wm * 64 + mt * 16 + l15;
        int ch  = (kf * 2 + (quad >> 1)) ^ r7;
        av[mt] = *(const long*)&sA[row * 128 + ch * 16 + (quad & 1) * 8];
      }
#pragma unroll
      for (int nt = 0; nt < 4; ++nt) {
        int row = wn * 64 + nt * 16 + l15;
        int ch  = (kf * 2 + (quad >> 1)) ^ r7;
        bvv[nt] = *(const long*)&sB[row * 128 + ch * 16 + (quad & 1) * 8];
      }
#pragma unroll
      for (int mt = 0; mt < 4; ++mt)
#pragma unroll
        for (int nt = 0; nt < 4; ++nt)
          acc[mt][nt] = __builtin_amdgcn_mfma_f32_16x16x32_fp8_fp8(av[mt], bvv[nt], acc[mt][nt], 0, 0, 0);
    }
    asm volatile("" ::: "memory");
    __builtin_amdgcn_s_barrier();
    asm volatile("" ::: "memory");
    cur ^= 1;
  }

  // ---- epilogue: C/D layout col=lane&15, row=quad*4+reg ----
  if (MODE == 1) {
    float lsum[4][4];
#pragma unroll
    for (int mt = 0; mt < 4; ++mt)
#pragma unroll
      for (int r = 0; r < 4; ++r) lsum[mt][r] = 0.0f;
#pragma unroll
    for (int nt = 0; nt < 4; ++nt) {
      int gc = j0 + wn * 64 + nt * 16 + l15;
#pragma unroll
      for (int mt = 0; mt < 4; ++mt) {
        int gr0 = i0 + wm * 64 + mt * 16 + quad * 4;
#pragma unroll
        for (int r = 0; r < 4; ++r) {
          int row = gr0 + r;
          float e = (gc >= row) ? __expf(acc[mt][nt][r] - 4.0f) : 0.0f;
          unsigned char eb = f2fp8(e);
          Cb[(size_t)row * ldc + gc] = eb;
          lsum[mt][r] += fp82f(eb);  // sum what PV will actually read
        }
      }
    }
#pragma unroll
    for (int mt = 0; mt < 4; ++mt)
#pragma unroll
      for (int r = 0; r < 4; ++r) {
        float s = lsum[mt][r];
        s += __shfl_xor(s, 1);
        s += __shfl_xor(s, 2);
        s += __shfl_xor(s, 4);
        s += __shfl_xor(s, 8);
        if (l15 == 0)
          unsafeAtomicAdd(&lrow[i0 + wm * 64 + mt * 16 + quad * 4 + r], s);
      }
  } else {
    float inv[4][4];
#pragma unroll
    for (int mt = 0; mt < 4; ++mt)
#pragma unroll
      for (int r = 0; r < 4; ++r)
        inv[mt][r] = 1.0f / lrow[i0 + wm * 64 + mt * 16 + quad * 4 + r];
#pragma unroll
    for (int nt = 0; nt < 4; ++nt) {
      int gc = j0 + wn * 64 + nt * 16 + l15;
#pragma unroll
      for (int mt = 0; mt < 4; ++mt) {
        int gr0 = i0 + wm * 64 + mt * 16 + quad * 4;
#pragma unroll
        for (int r = 0; r < 4; ++r)
          unsafeAtomicAdd(&Cf[(size_t)(gr0 + r) * ldc + ccol + gc],
                          acc[mt][nt][r] * inv[mt][r]);
      }
    }
  }
}

extern "C" void kernel_launch(void* const* d_in, const int* in_sizes, int n_in,
                              void* d_out, int out_size, void* d_ws, size_t ws_size,
                              hipStream_t stream) {
  const float* x  = (const float*)d_in[0];
  const float* Wk = (const float*)d_in[1];
  const float* bk = (const float*)d_in[2];
  const float* Wq = (const float*)d_in[3];
  const float* bq = (const float*)d_in[4];
  const float* Wv = (const float*)d_in[5];
  const float* bv = (const float*)d_in[6];
  float* out = (float*)d_out;

  char* ws = (char*)d_ws;
  unsigned short* Xb   = (unsigned short*)(ws);                  // 8 MB  [4096][1024] bf16
  float*          lrow = (float*)(ws);                           // 16 KB, aliases Xb (dead after QKV)
  unsigned short* Wcat = (unsigned short*)(ws + (8ull << 20));   // 6 MB  [3072][1024] bf16
  float*          bcat = (float*)(ws + (14ull << 20));           // 12 KB
  unsigned char*  Qf8  = (unsigned char*)(ws + (15ull << 20));   // 4 MB  [4096][1024] fp8
  unsigned char*  Kf8  = (unsigned char*)(ws + (19ull << 20));   // 4 MB  [4096][1024] fp8
  unsigned short* Vb   = (unsigned short*)(ws + (23ull << 20));  // 8 MB  [4096][1024] bf16
  unsigned char*  Vt   = (unsigned char*)(ws + (31ull << 20));   // 4 MB  [1024][4096] fp8
  unsigned char*  Pr   = (unsigned char*)(ws + (35ull << 20));   // 16 MB [4096][4096] fp8

  // 1. x -> bf16 ; out[:, :1024] = x ; out[:, 1024:] = 0
  convert_x_kernel<<<SEQ * DIM / 4 / 256, 256, 0, stream>>>(x, Xb, out);

  // 2. W transposes + bias concat (one dispatch)
  prep_kernel<<<3084, 256, 0, stream>>>(Wq, Wk, Wv, bq, bk, bv, Wcat, bcat);

  // 3. fused QKV GEMM (bf16) -> Qf8 (x1/32), Kf8, Vb
  gemm_qkv<<<dim3(24, 32), 256, 0, stream>>>(Xb, Wcat, bcat, Qf8, Kf8, Vb);

  // 4. Vt = V^T as fp8; also zeroes lrow (aliases dead Xb)
  transpose_v_kernel<<<dim3(DIM / 32, SEQ / 32), 256, 0, stream>>>(
      Vb, DIM, Vt, SEQ, lrow);

  // 5. scores upper-tri tiles (fp8) + fused exp + row-sum accumulation
  gemm_fp8<1><<<528, 256, 0, stream>>>(
      Qf8, DIM, Kf8, DIM, Pr, nullptr, lrow, SEQ, 0, DIM);

  // 6. read = (expS @ V) / l -> out[:, 1024:2048] (fp8 mfma, fp32 atomics)
  gemm_fp8<2><<<dim3(8, 32, 4), 256, 0, stream>>>(
      Pr, SEQ, Vt, SEQ, nullptr, out, lrow, 2048, 1024, SEQ);
}

// Round 2
// 206.322 us; speedup vs baseline: 1.1142x; 1.0398x over previous
//
#include <hip/hip_runtime.h>
#include <hip/hip_bf16.h>
#include <hip/hip_fp8.h>

#define SEQ 4096
#define DIM 1024

using f32x4  = __attribute__((ext_vector_type(4))) float;
using bf16x8 = __attribute__((ext_vector_type(8))) short;

static __device__ __forceinline__ float bf2f(unsigned short u) {
  unsigned int x = ((unsigned int)u) << 16;
  return __builtin_bit_cast(float, x);
}
static __device__ __forceinline__ unsigned short f2bf(float f) {
  unsigned int x = __builtin_bit_cast(unsigned int, f);
  unsigned int r = (x + 0x7fff + ((x >> 16) & 1)) >> 16;  // RNE
  return (unsigned short)r;
}
static __device__ __forceinline__ unsigned char f2fp8(float f) {
  __hip_fp8_e4m3 h(f);  // OCP e4m3fn
  return h.__x;
}
static __device__ __forceinline__ float fp82f(unsigned char u) {
  __hip_fp8_e4m3 h;
  h.__x = u;
  return (float)h;
}

// ---- fused prep: x->bf16 + out[:, :1024]=x ; 3x W transpose ; bias ; lrow=0 ----
// blocks [0,4096): convert x ; [4096,7168): W transpose ; [7168,7180): bias ;
// [7180,7196): zero lrow. (out[:,1024:2048] is fully written by gemm_pv - no
// zero-fill needed.)
__global__ __launch_bounds__(256) void prep_all(
    const float* __restrict__ x, const float* __restrict__ Wq,
    const float* __restrict__ Wk, const float* __restrict__ Wv,
    const float* __restrict__ bq, const float* __restrict__ bk,
    const float* __restrict__ bv, unsigned short* __restrict__ xb,
    float* __restrict__ out, unsigned short* __restrict__ Wcat,
    float* __restrict__ bcat, float* __restrict__ lrow) {
  int b = blockIdx.x;
  if (b < 4096) {
    int idx = b * 256 + threadIdx.x;  // one thread per 4 floats
    int e = idx * 4;
    int i = e >> 10;
    int d = e & 1023;
    float4 v = *(const float4*)(x + (size_t)e);
    *(float4*)(out + (size_t)i * 2048 + d) = v;
    ushort4 p;
    p.x = f2bf(v.x); p.y = f2bf(v.y); p.z = f2bf(v.z); p.w = f2bf(v.w);
    *(ushort4*)(xb + (size_t)e) = p;
  } else if (b < 7168) {
    int tt = b - 4096;
    int m  = tt >> 10;
    tt &= 1023;
    const float* in = (m == 0) ? Wq : (m == 1) ? Wk : Wv;
    unsigned short* o = Wcat + (size_t)m * DIM * DIM;
    __shared__ float tile[32][33];
    int bx = (tt & 31) * 32, by = (tt >> 5) * 32;
    int tx = threadIdx.x & 31, ty = threadIdx.x >> 5;
#pragma unroll
    for (int r = 0; r < 32; r += 8)
      tile[ty + r][tx] = in[(size_t)(by + ty + r) * DIM + bx + tx];
    __syncthreads();
#pragma unroll
    for (int r = 0; r < 32; r += 8)
      o[(size_t)(bx + ty + r) * DIM + by + tx] = f2bf(tile[tx][ty + r]);
  } else if (b < 7180) {
    int i = (b - 7168) * 256 + threadIdx.x;  // 12 blocks -> 3072 elems
    float v = (i < 1024) ? bq[i] : (i < 2048 ? bk[i - 1024] : bv[i - 2048]);
    bcat[i] = v;
  } else {
    int i = (b - 7180) * 256 + threadIdx.x;  // 16 blocks -> 4096 elems
    lrow[i] = 0.0f;
  }
}

// ---- QKV GEMM (bf16, BK=64, 8-slot XOR swizzle, 2-phase dbuf pipeline) ----
// C = Xb @ Wcat^T + bcat; epilogue: Q cols -> fp8 (x1/32), K cols -> fp8,
// V cols -> Vt fp8 TRANSPOSED (packed dword stores) - transpose_v fused away.
__global__ __launch_bounds__(256) void gemm_qkv(
    const unsigned short* __restrict__ A, const unsigned short* __restrict__ B,
    const float* __restrict__ bias,
    unsigned char* __restrict__ Qf8, unsigned char* __restrict__ Kf8,
    unsigned char* __restrict__ Vt) {
  const int tid  = threadIdx.x;
  const int wave = tid >> 6;
  const int lane = tid & 63;
  const int wm = wave >> 1, wn = wave & 1;

  int lin = blockIdx.x + 24 * blockIdx.y;
  int xcd = lin & 7, idx = lin >> 3;  // idx in [0,96)
  const int i0 = (xcd * 4 + idx / 24) * 128;
  const int j0 = (idx % 24) * 128;
  const int lda = DIM, ldb = DIM;

  __shared__ unsigned short lA[2][128 * 64];  // 2 x 16 KB
  __shared__ unsigned short lB[2][128 * 64];  // 2 x 16 KB

  f32x4 acc[4][4];
#pragma unroll
  for (int a = 0; a < 4; ++a)
#pragma unroll
    for (int b = 0; b < 4; ++b) acc[a][b] = (f32x4){0.f, 0.f, 0.f, 0.f};

  const int l15  = lane & 15;
  const int quad = lane >> 4;
  const int r7   = l15 & 7;
  const int cbase = wave * 256;

  auto stage = [&](int buf, int kt) {
    const unsigned short* gA = A + (size_t)i0 * lda + kt;
    const unsigned short* gB = B + (size_t)j0 * ldb + kt;
#pragma unroll
    for (int t = 0; t < 4; ++t) {
      int c  = cbase + t * 64 + lane;
      int r  = c >> 3;
      int g  = (c & 7) ^ (r & 7);
      __builtin_amdgcn_global_load_lds(
          (const __attribute__((address_space(1))) void*)(gA + (size_t)r * lda + g * 8),
          (__attribute__((address_space(3))) void*)(&lA[buf][c * 8]), 16, 0, 0);
      __builtin_amdgcn_global_load_lds(
          (const __attribute__((address_space(1))) void*)(gB + (size_t)r * ldb + g * 8),
          (__attribute__((address_space(3))) void*)(&lB[buf][c * 8]), 16, 0, 0);
    }
  };

  stage(0, 0);
  int cur = 0;
  for (int kt = 0; kt < DIM; kt += 64) {
    if (kt + 64 < DIM) {
      stage(cur ^ 1, kt + 64);
      asm volatile("s_waitcnt vmcnt(8)" ::: "memory");  // current tile landed
    } else {
      asm volatile("s_waitcnt vmcnt(0)" ::: "memory");
    }
    __builtin_amdgcn_s_barrier();
    asm volatile("" ::: "memory");
    const unsigned short* sA = lA[cur];
    const unsigned short* sB = lB[cur];
#pragma unroll
    for (int kf = 0; kf < 2; ++kf) {
      bf16x8 af[4], bfr[4];
#pragma unroll
      for (int mt = 0; mt < 4; ++mt)
        af[mt] = *(const bf16x8*)&sA[(wm * 64 + mt * 16 + l15) * 64 + ((kf * 4 + quad) ^ r7) * 8];
#pragma unroll
      for (int nt = 0; nt < 4; ++nt)
        bfr[nt] = *(const bf16x8*)&sB[(wn * 64 + nt * 16 + l15) * 64 + ((kf * 4 + quad) ^ r7) * 8];
#pragma unroll
      for (int mt = 0; mt < 4; ++mt)
#pragma unroll
        for (int nt = 0; nt < 4; ++nt)
          acc[mt][nt] = __builtin_amdgcn_mfma_f32_16x16x32_bf16(af[mt], bfr[nt], acc[mt][nt], 0, 0, 0);
    }
    asm volatile("" ::: "memory");
    __builtin_amdgcn_s_barrier();
    asm volatile("" ::: "memory");
    cur ^= 1;
  }

  // epilogue: route to Qf8 / Kf8 / Vt (matrix select is wave-uniform per nt)
#pragma unroll
  for (int nt = 0; nt < 4; ++nt) {
    int cb  = j0 + wn * 64 + nt * 16;  // 16-col tile lies in one matrix
    int mat = cb >> 10;                // 0=Q, 1=K, 2=V
    int gc  = cb + l15;
    float bv = bias[gc];
    if (mat == 0) {
#pragma unroll
      for (int mt = 0; mt < 4; ++mt) {
        int gr0 = i0 + wm * 64 + mt * 16 + quad * 4;
#pragma unroll
        for (int r = 0; r < 4; ++r)
          Qf8[(size_t)(gr0 + r) * DIM + gc] = f2fp8((acc[mt][nt][r] + bv) * 0.03125f);
      }
    } else if (mat == 1) {
#pragma unroll
      for (int mt = 0; mt < 4; ++mt) {
        int gr0 = i0 + wm * 64 + mt * 16 + quad * 4;
#pragma unroll
        for (int r = 0; r < 4; ++r)
          Kf8[(size_t)(gr0 + r) * DIM + (gc - 1024)] = f2fp8(acc[mt][nt][r] + bv);
      }
    } else {
      // V: write transposed fp8 directly. Lane's 4 acc rows (quad*4+r) are 4
      // consecutive bytes of Vt row (gc-2048) -> one packed dword store.
      size_t vbase = (size_t)(gc - 2048) * SEQ;
#pragma unroll
      for (int mt = 0; mt < 4; ++mt) {
        int gr0 = i0 + wm * 64 + mt * 16 + quad * 4;
        unsigned int pk = 0;
#pragma unroll
        for (int r = 0; r < 4; ++r)
          pk |= (unsigned int)f2fp8(acc[mt][nt][r] + bv) << (8 * r);
        *(unsigned int*)(Vt + vbase + gr0) = pk;
      }
    }
  }
}

// ---- scores GEMM (fp8, BK=128, 8-slot XOR swizzle, 2-phase dbuf) ----
// 528 upper-tri tiles (66/XCD). Epilogue: e=exp(S-4) fp8 into Pr, row-sums
// atomically into lrow.
__global__ __launch_bounds__(256) void gemm_scores(
    const unsigned char* __restrict__ A, const unsigned char* __restrict__ B,
    unsigned char* __restrict__ Cb, float* __restrict__ lrow) {
  const int tid  = threadIdx.x;
  const int wave = tid >> 6;
  const int lane = tid & 63;
  const int wm = wave >> 1, wn = wave & 1;
  const int lda = DIM, ldb = DIM, ldc = SEQ;

  int b = blockIdx.x;
  int t0 = (b & 7) * 66 + (b >> 3);
  int bi = (int)floorf((65.0f - sqrtf(4225.0f - 8.0f * (float)t0)) * 0.5f);
  while (bi > 0 && (bi * (65 - bi)) / 2 > t0) --bi;
  while (((bi + 1) * (64 - bi)) / 2 <= t0) ++bi;
  int bj = bi + (t0 - (bi * (65 - bi)) / 2);
  const int i0 = bi * 128, j0 = bj * 128;

  __shared__ unsigned char lA[2][128 * 128];  // 2 x 16 KB
  __shared__ unsigned char lB[2][128 * 128];  // 2 x 16 KB

  f32x4 acc[4][4];
#pragma unroll
  for (int a = 0; a < 4; ++a)
#pragma unroll
    for (int c = 0; c < 4; ++c) acc[a][c] = (f32x4){0.f, 0.f, 0.f, 0.f};

  const int l15  = lane & 15;
  const int quad = lane >> 4;
  const int r7   = l15 & 7;
  const int cbase = wave * 256;

  auto stage = [&](int buf, int kt) {
    const unsigned char* gA = A + (size_t)i0 * lda + kt;
    const unsigned char* gB = B + (size_t)j0 * ldb + kt;
#pragma unroll
    for (int t = 0; t < 4; ++t) {
      int c  = cbase + t * 64 + lane;
      int r  = c >> 3;
      int g  = (c & 7) ^ (r & 7);
      __builtin_amdgcn_global_load_lds(
          (const __attribute__((address_space(1))) void*)(gA + (size_t)r * lda + g * 16),
          (__attribute__((address_space(3))) void*)(&lA[buf][c * 16]), 16, 0, 0);
      __builtin_amdgcn_global_load_lds(
          (const __attribute__((address_space(1))) void*)(gB + (size_t)r * ldb + g * 16),
          (__attribute__((address_space(3))) void*)(&lB[buf][c * 16]), 16, 0, 0);
    }
  };

  stage(0, 0);
  int cur = 0;
  for (int kt = 0; kt < DIM; kt += 128) {
    if (kt + 128 < DIM) {
      stage(cur ^ 1, kt + 128);
      asm volatile("s_waitcnt vmcnt(8)" ::: "memory");
    } else {
      asm volatile("s_waitcnt vmcnt(0)" ::: "memory");
    }
    __builtin_amdgcn_s_barrier();
    asm volatile("" ::: "memory");
    const unsigned char* sA = lA[cur];
    const unsigned char* sB = lB[cur];
#pragma unroll
    for (int kf = 0; kf < 4; ++kf) {
      long av[4], bvv[4];
#pragma unroll
      for (int mt = 0; mt < 4; ++mt) {
        int row = wm * 64 + mt * 16 + l15;
        int ch  = (kf * 2 + (quad >> 1)) ^ r7;
        av[mt] = *(const long*)&sA[row * 128 + ch * 16 + (quad & 1) * 8];
      }
#pragma unroll
      for (int nt = 0; nt < 4; ++nt) {
        int row = wn * 64 + nt * 16 + l15;
        int ch  = (kf * 2 + (quad >> 1)) ^ r7;
        bvv[nt] = *(const long*)&sB[row * 128 + ch * 16 + (quad & 1) * 8];
      }
#pragma unroll
      for (int mt = 0; mt < 4; ++mt)
#pragma unroll
        for (int nt = 0; nt < 4; ++nt)
          acc[mt][nt] = __builtin_amdgcn_mfma_f32_16x16x32_fp8_fp8(av[mt], bvv[nt], acc[mt][nt], 0, 0, 0);
    }
    asm volatile("" ::: "memory");
    __builtin_amdgcn_s_barrier();
    asm volatile("" ::: "memory");
    cur ^= 1;
  }

  // epilogue: C/D layout col=lane&15, row=quad*4+reg
  float lsum[4][4];
#pragma unroll
  for (int mt = 0; mt < 4; ++mt)
#pragma unroll
    for (int r = 0; r < 4; ++r) lsum[mt][r] = 0.0f;
#pragma unroll
  for (int nt = 0; nt < 4; ++nt) {
    int gc = j0 + wn * 64 + nt * 16 + l15;
#pragma unroll
    for (int mt = 0; mt < 4; ++mt) {
      int gr0 = i0 + wm * 64 + mt * 16 + quad * 4;
#pragma unroll
      for (int r = 0; r < 4; ++r) {
        int row = gr0 + r;
        float e = (gc >= row) ? __expf(acc[mt][nt][r] - 4.0f) : 0.0f;
        unsigned char eb = f2fp8(e);
        Cb[(size_t)row * ldc + gc] = eb;
        lsum[mt][r] += fp82f(eb);  // sum what PV will actually read
      }
    }
  }
#pragma unroll
  for (int mt = 0; mt < 4; ++mt)
#pragma unroll
    for (int r = 0; r < 4; ++r) {
      float s = lsum[mt][r];
      s += __shfl_xor(s, 1);
      s += __shfl_xor(s, 2);
      s += __shfl_xor(s, 4);
      s += __shfl_xor(s, 8);
      if (l15 == 0)
        unsafeAtomicAdd(&lrow[i0 + wm * 64 + mt * 16 + quad * 4 + r], s);
    }
}

// ---- PV GEMM (fp8), balanced triangular pairing, NO split-K, NO atomics ----
// Block = (pair p, 64-col chunk j). Computes row-tile p (32-p steps) then
// row-tile 31-p (p+1 steps) = constant 33 K-steps. 256 blocks = 1 round.
// 2-deep prefetch (3 LDS buffers, vmcnt(12)) to cover latency at 1 blk/CU.
// Epilogue: scale by 1/lrow, plain f32 stores into out[:, 1024+j0 ...].
__global__ __launch_bounds__(256) void gemm_pv(
    const unsigned char* __restrict__ P,   // [4096][4096] fp8
    const unsigned char* __restrict__ Vt,  // [1024][4096] fp8
    const float* __restrict__ lrow,
    float* __restrict__ out) {             // [4096][2048]
  const int tid  = threadIdx.x;
  const int wave = tid >> 6;  // row group: rows [wave*32, wave*32+32)
  const int lane = tid & 63;
  const int l15  = lane & 15;
  const int quad = lane >> 4;
  const int r7   = l15 & 7;

  int wgid = (blockIdx.x & 7) * 32 + (blockIdx.x >> 3);  // XCD-contiguous
  const int p   = wgid & 15;
  const int j0  = (wgid >> 4) * 64;  // Vt row base == out col offset
  const int i0a = p * 128;
  const int i0b = (31 - p) * 128;
  const int n1  = 32 - p;  // steps for tile a
  const int n   = 33;      // total steps

  __shared__ unsigned char lA[3][128 * 128];  // 48 KB
  __shared__ unsigned char lB[3][64 * 128];   // 24 KB

  f32x4 accA[2][4], accB[2][4];
#pragma unroll
  for (int a = 0; a < 2; ++a)
#pragma unroll
    for (int c = 0; c < 4; ++c) {
      accA[a][c] = (f32x4){0.f, 0.f, 0.f, 0.f};
      accB[a][c] = (f32x4){0.f, 0.f, 0.f, 0.f};
    }

  auto stage = [&](int buf, int t) {
    int ib = (t < n1) ? i0a : i0b;
    int kt = (t < n1) ? i0a + t * 128 : i0b + (t - n1) * 128;
    const unsigned char* gA = P + (size_t)ib * SEQ + kt;
    const unsigned char* gB = Vt + (size_t)j0 * SEQ + kt;
#pragma unroll
    for (int c4 = 0; c4 < 4; ++c4) {  // A: 1024 16B chunks
      int c = c4 * 256 + tid;
      int r = c >> 3;
      int g = (c & 7) ^ (r & 7);
      __builtin_amdgcn_global_load_lds(
          (const __attribute__((address_space(1))) void*)(gA + (size_t)r * SEQ + g * 16),
          (__attribute__((address_space(3))) void*)(&lA[buf][c * 16]), 16, 0, 0);
    }
#pragma unroll
    for (int c2 = 0; c2 < 2; ++c2) {  // B: 512 16B chunks
      int c = c2 * 256 + tid;
      int r = c >> 3;
      int g = (c & 7) ^ (r & 7);
      __builtin_amdgcn_global_load_lds(
          (const __attribute__((address_space(1))) void*)(gB + (size_t)r * SEQ + g * 16),
          (__attribute__((address_space(3))) void*)(&lB[buf][c * 16]), 16, 0, 0);
    }
  };

  auto compute = [&](int buf, f32x4 (&acc)[2][4]) {
    const unsigned char* sA = lA[buf];
    const unsigned char* sB = lB[buf];
#pragma unroll
    for (int kf = 0; kf < 4; ++kf) {
      long av[2], bvv[4];
      int ch = (kf * 2 + (quad >> 1)) ^ r7;
#pragma unroll
      for (int mt = 0; mt < 2; ++mt) {
        int row = wave * 32 + mt * 16 + l15;
        av[mt] = *(const long*)&sA[row * 128 + ch * 16 + (quad & 1) * 8];
      }
#pragma unroll
      for (int nt = 0; nt < 4; ++nt) {
        int row = nt * 16 + l15;
        bvv[nt] = *(const long*)&sB[row * 128 + ch * 16 + (quad & 1) * 8];
      }
#pragma unroll
      for (int mt = 0; mt < 2; ++mt)
#pragma unroll
        for (int nt = 0; nt < 4; ++nt)
          acc[mt][nt] = __builtin_amdgcn_mfma_f32_16x16x32_fp8_fp8(av[mt], bvv[nt], acc[mt][nt], 0, 0, 0);
    }
  };

  stage(0, 0);
  stage(1, 1);
  for (int t = 0; t < n; ++t) {
    if (t + 2 < n) {
      stage((t + 2) % 3, t + 2);
      asm volatile("s_waitcnt vmcnt(12)" ::: "memory");  // step t's loads done
    } else if (t + 1 < n) {
      asm volatile("s_waitcnt vmcnt(6)" ::: "memory");
    } else {
      asm volatile("s_waitcnt vmcnt(0)" ::: "memory");
    }
    __builtin_amdgcn_s_barrier();
    asm volatile("" ::: "memory");
    if (t < n1) compute(t % 3, accA);
    else        compute(t % 3, accB);
    asm volatile("" ::: "memory");
    __builtin_amdgcn_s_barrier();
    asm volatile("" ::: "memory");
  }

  // epilogue: plain stores, scaled by 1/lrow. C layout col=l15, row=quad*4+r.
#pragma unroll
  for (int mt = 0; mt < 2; ++mt) {
#pragma unroll
    for (int r = 0; r < 4; ++r) {
      int rowa = i0a + wave * 32 + mt * 16 + quad * 4 + r;
      int rowb = i0b + wave * 32 + mt * 16 + quad * 4 + r;
      float ia = 1.0f / lrow[rowa];
      float ib = 1.0f / lrow[rowb];
#pragma unroll
      for (int nt = 0; nt < 4; ++nt) {
        int gc = 1024 + j0 + nt * 16 + l15;
        out[(size_t)rowa * 2048 + gc] = accA[mt][nt][r] * ia;
        out[(size_t)rowb * 2048 + gc] = accB[mt][nt][r] * ib;
      }
    }
  }
}

extern "C" void kernel_launch(void* const* d_in, const int* in_sizes, int n_in,
                              void* d_out, int out_size, void* d_ws, size_t ws_size,
                              hipStream_t stream) {
  const float* x  = (const float*)d_in[0];
  const float* Wk = (const float*)d_in[1];
  const float* bk = (const float*)d_in[2];
  const float* Wq = (const float*)d_in[3];
  const float* bq = (const float*)d_in[4];
  const float* Wv = (const float*)d_in[5];
  const float* bv = (const float*)d_in[6];
  float* out = (float*)d_out;

  char* ws = (char*)d_ws;
  unsigned short* Xb   = (unsigned short*)(ws);                          // 8 MB  [4096][1024] bf16
  unsigned short* Wcat = (unsigned short*)(ws + (8ull << 20));           // 6 MB  [3072][1024] bf16
  float*          bcat = (float*)(ws + (14ull << 20));                   // 12 KB
  float*          lrow = (float*)(ws + (14ull << 20) + (64ull << 10));   // 16 KB
  unsigned char*  Qf8  = (unsigned char*)(ws + (15ull << 20));           // 4 MB  [4096][1024] fp8
  unsigned char*  Kf8  = (unsigned char*)(ws + (19ull << 20));           // 4 MB  [4096][1024] fp8
  unsigned char*  Vt   = (unsigned char*)(ws + (23ull << 20));           // 4 MB  [1024][4096] fp8
  unsigned char*  Pr   = (unsigned char*)(ws + (27ull << 20));           // 16 MB [4096][4096] fp8

  // 1. x->bf16 + out[:, :1024]=x ; W transposes ; bias concat ; lrow=0
  prep_all<<<7196, 256, 0, stream>>>(x, Wq, Wk, Wv, bq, bk, bv,
                                     Xb, out, Wcat, bcat, lrow);

  // 2. fused QKV GEMM (bf16) -> Qf8 (x1/32), Kf8, Vt (fp8 transposed)
  gemm_qkv<<<dim3(24, 32), 256, 0, stream>>>(Xb, Wcat, bcat, Qf8, Kf8, Vt);

  // 3. scores upper-tri tiles (fp8) + fused exp + row-sum accumulation
  gemm_scores<<<528, 256, 0, stream>>>(Qf8, Kf8, Pr, lrow);

  // 4. read = (expS @ V) / l -> out[:, 1024:2048], balanced pairs, no atomics
  gemm_pv<<<256, 256, 0, stream>>>(Pr, Vt, lrow, out);
}